// Round 4
// baseline (460.261 us; speedup 1.0000x reference)
//
#include <hip/hip_runtime.h>
#include <math.h>

#define Bc 4
#define Lc 4096
#define Dc 1024
#define Mtot (Bc*Lc)          // 16384 flattened tokens
#define NSEG 128
#define SEGLEN (Lc/NSEG)      // 32

typedef __attribute__((ext_vector_type(8))) short short8;
typedef __attribute__((ext_vector_type(4))) float floatx4;
typedef unsigned short us;

// ---- workspace layout (bytes) — total ~42.2 MB ----
#define OFF_QH    ((size_t)0)          // 1024x1024 bf16
#define OFF_KH    ((size_t)2097152)
#define OFF_XBF   ((size_t)4194304)    // Mtot x 1024 bf16 (32 MB)
#define OFF_PARTS ((size_t)37748736)   // 3*Mtot f32 (dot,qn,kn)
#define OFF_FLAGS ((size_t)37945344)   // int count + 2048 idx (8448 B)
#define OFF_COSV  ((size_t)37953792)   // Mtot f32
#define OFF_ASEG  ((size_t)38019328)   // Bc*NSEG f32 (2 KB)
#define OFF_BSEG  ((size_t)38021376)   // Bc*NSEG*Dc f32 (2 MB)
#define OFF_CARRY ((size_t)40118528)   // 2 MB

// ---------------------------------------------------------------------------
__device__ inline us f2bf(float x) {
    unsigned int u = __float_as_uint(x);
    u += 0x7FFFu + ((u >> 16) & 1u);
    return (us)(u >> 16);
}

// ---------------------------------------------------------------------------
// prep: Qw/Kw fp32 -> bf16, X fp32 -> bf16 (one-shot, hoisted out of GEMM),
// zero parts + flags.
// ---------------------------------------------------------------------------
__global__ __launch_bounds__(256)
void prep_kernel(const float* __restrict__ Qw, const float* __restrict__ Kw,
                 const float* __restrict__ X,
                 us* __restrict__ Qh, us* __restrict__ Kh, us* __restrict__ Xbf,
                 float* __restrict__ parts, int* __restrict__ flags)
{
    const int bid = blockIdx.x, tid = threadIdx.x;
    if (bid < 512) {
        const float* W = (bid < 256) ? Qw : Kw;
        us* Wh = (bid < 256) ? Qh : Kh;
        const int lb = bid & 255;
        #pragma unroll
        for (int k = 0; k < 4; ++k) {
            const size_t e4 = (size_t)lb*1024 + k*256 + tid;
            const float4 v = *(const float4*)&W[e4*4];
            ushort4 h;
            h.x = f2bf(v.x); h.y = f2bf(v.y); h.z = f2bf(v.z); h.w = f2bf(v.w);
            *(ushort4*)&Wh[e4*4] = h;
        }
    } else if (bid < 704) {
        const int idx = (bid - 512)*256 + tid;
        if (idx < 3*Mtot) parts[idx] = 0.f;
        if (idx == 0) flags[0] = 0;
    } else {
        const int xb = bid - 704;                   // 0..2047
        const float4* src = (const float4*)X;
        ushort4* dst = (ushort4*)Xbf;
        #pragma unroll
        for (int j = 0; j < 8; ++j) {
            const size_t f = (size_t)xb*2048 + j*256 + tid;
            const float4 v = src[f];
            ushort4 h;
            h.x = f2bf(v.x); h.y = f2bf(v.y); h.z = f2bf(v.z); h.w = f2bf(v.w);
            dst[f] = h;
        }
    }
}

// ---------------------------------------------------------------------------
// Single-product bf16 MFMA GEMM: q_t = Qw.x_t, k'_t = Kw.x_{t+1}.
// A (X tile, 129x32, +1-row halo) AND B (Q,K weight tiles) both staged via
// global_load_lds from pre-converted bf16, with pre-swizzled per-lane source
// addresses (granule-XOR (row>>1)&3) -> linear LDS dest, conflict-free reads.
// Per-lane staging pointers precomputed, marched +64B/chunk: ~no in-loop VALU.
// Tiles: 128(M) x 128(N), BK=32. LDS = (516 + 1024) granules = 24,640 B.
// ---------------------------------------------------------------------------
#define AS1C const __attribute__((address_space(1))) void*
#define AS3P __attribute__((address_space(3))) void*

__global__ __launch_bounds__(256, 2)
void gemm_cos_kernel(const us* __restrict__ Xbf,
                     const us* __restrict__ Qh,
                     const us* __restrict__ Kh,
                     float* __restrict__ parts)
{
    __shared__ __align__(16) us lds[12320];
    us* AsH = lds;                 // 516 granules: (row,c) at row*32 + c*8
    us* Bs  = lds + 4128;          // 1024 granules: Q tile then K tile

    const int tid  = threadIdx.x;
    const int lane = tid & 63;
    const int wv   = tid >> 6;
    const int wm   = wv >> 1;
    const int wn   = wv & 1;
    // XCD-aware swizzle (1024 % 8 == 0 -> bijective)
    const int swz  = ((blockIdx.x & 7) << 7) | (blockIdx.x >> 3);
    const int bm   = swz >> 3;
    const int bn   = swz & 7;
    const int t0   = bm * 128;
    const int nb   = bn * 128;

    floatx4 accq[4][4], acck[4][4];
    const floatx4 zz = {0.f, 0.f, 0.f, 0.f};
    #pragma unroll
    for (int i = 0; i < 4; i++)
        #pragma unroll
        for (int j = 0; j < 4; j++) { accq[i][j] = zz; acck[i][j] = zz; }

    // ---- staging source pointers (per-lane, pre-swizzled), marched /chunk ----
    // A granule g: row=g>>2, c=g&3; source column-granule = c ^ ((row>>1)&3)
    const int r0 = tid >> 2, c0 = tid & 3;
    const int r1 = r0 + 64;
    const us* pA0 = Xbf + (size_t)(t0 + r0)*Dc + ((c0 ^ ((r0 >> 1) & 3)) << 3);
    const us* pA1 = Xbf + (size_t)(t0 + r1)*Dc + ((c0 ^ ((r1 >> 1) & 3)) << 3);
    int ta2 = t0 + 128; if (ta2 >= Mtot) ta2 = Mtot - 1;   // halo row clamp
    const us* pA2 = Xbf + (size_t)ta2*Dc + ((tid & 3) << 3); // (128>>1)&3 == 0
    const us* pB[4];
    #pragma unroll
    for (int it = 0; it < 4; ++it) {
        const int g   = it*256 + tid;
        const us* wbase = (g & 512) ? Kh : Qh;
        const int gg  = g & 511;
        const int row = gg >> 2;
        const int sl  = (gg & 3) ^ ((row >> 1) & 3);
        pB[it] = wbase + (size_t)(nb + row)*Dc + (sl << 3);
    }

    const int lrow = lane & 15;
    const int lg   = lane >> 4;    // k-granule 0..3 (8 shorts each)

    for (int ch = 0; ch < 32; ++ch) {
        // ---- stage A + B via global_load_lds (7 issues/thread) ----
        __builtin_amdgcn_global_load_lds((AS1C)pA0, (AS3P)(AsH + tid*8),       16, 0, 0);
        __builtin_amdgcn_global_load_lds((AS1C)pA1, (AS3P)(AsH + (tid+256)*8), 16, 0, 0);
        if (tid < 4)
            __builtin_amdgcn_global_load_lds((AS1C)pA2, (AS3P)(AsH + (tid+512)*8), 16, 0, 0);
        #pragma unroll
        for (int it = 0; it < 4; ++it)
            __builtin_amdgcn_global_load_lds((AS1C)pB[it], (AS3P)(Bs + (it*256 + tid)*8), 16, 0, 0);
        pA0 += 32; pA1 += 32; pA2 += 32;
        pB[0] += 32; pB[1] += 32; pB[2] += 32; pB[3] += 32;
        __syncthreads();

        short8 aq[4], ak[4];
        #pragma unroll
        for (int i = 0; i < 4; ++i) {
            const int r  = wm*64 + i*16 + lrow;
            const int r1f = r + 1;
            aq[i] = *(const short8*)&AsH[r  *32 + ((lg ^ ((r   >> 1) & 3)) << 3)];
            ak[i] = *(const short8*)&AsH[r1f*32 + ((lg ^ ((r1f >> 1) & 3)) << 3)];
        }
        #pragma unroll
        for (int j = 0; j < 4; ++j) {
            const int rn = wn*64 + j*16 + lrow;
            const int bo = rn*32 + ((lg ^ ((rn >> 1) & 3)) << 3);
            const short8 fbq = *(const short8*)&Bs[bo];
            const short8 fbk = *(const short8*)&Bs[4096 + bo];
            #pragma unroll
            for (int i = 0; i < 4; ++i) {
                accq[i][j] = __builtin_amdgcn_mfma_f32_16x16x32_bf16(aq[i], fbq, accq[i][j], 0, 0, 0);
                acck[i][j] = __builtin_amdgcn_mfma_f32_16x16x32_bf16(ak[i], fbk, acck[i][j], 0, 0, 0);
            }
        }
        __syncthreads();
    }

    // ---- epilogue: per-row dot/qn/kn over this WG's 128 cols, then atomics ----
    #pragma unroll
    for (int i = 0; i < 4; ++i) {
        #pragma unroll
        for (int reg = 0; reg < 4; ++reg) {
            float d = 0.f, qq = 0.f, kk = 0.f;
            #pragma unroll
            for (int j = 0; j < 4; ++j) {
                const float qv = accq[i][j][reg];
                const float kv = acck[i][j][reg];
                d  += qv * kv;
                qq += qv * qv;
                kk += kv * kv;
            }
            #pragma unroll
            for (int m = 1; m <= 8; m <<= 1) {
                d  += __shfl_xor(d,  m);
                qq += __shfl_xor(qq, m);
                kk += __shfl_xor(kk, m);
            }
            if ((lane & 15) == 0) {
                const int row = t0 + wm*64 + i*16 + ((lane >> 4) << 2) + reg;
                atomicAdd(&parts[row],          d);
                atomicAdd(&parts[Mtot + row],   qq);
                atomicAdd(&parts[2*Mtot + row], kk);
            }
        }
    }
}

// ---------------------------------------------------------------------------
// finalize cos + flag near-boundary tokens (|cos| < 1.2e-3 ~= 12 sigma of the
// single-product bf16 error); zero flagged parts so repair can re-accumulate.
// ---------------------------------------------------------------------------
__global__ __launch_bounds__(256)
void cos_fin_kernel(float* __restrict__ parts,
                    float* __restrict__ cosv,
                    int* __restrict__ flags)
{
    const int t = blockIdx.x*256 + threadIdx.x;
    if (t >= Mtot) return;
    const float dot = parts[t];
    const float qn  = parts[Mtot + t];
    const float kn  = parts[2*Mtot + t];
    const float c = dot / (fmaxf(sqrtf(qn), 1e-12f) * fmaxf(sqrtf(kn), 1e-12f));
    cosv[t] = c;
    if (fabsf(c) < 1.2e-3f && (t & (Lc-1)) != (Lc-1)) {
        const int idx = atomicAdd(flags, 1);
        if (idx < 2048) {
            flags[1 + idx] = t;
            parts[t] = 0.f; parts[Mtot + t] = 0.f; parts[2*Mtot + t] = 0.f;
        }
    }
}

// ---------------------------------------------------------------------------
// Wave-wide f32 sum with minimal LDS-pipe use: butterfly masks {1,2,7,15,16,32}
// (span all 6 lane bits). 1,2 = DPP quad_perm; 7,15 = DPP row_half_mirror /
// row_mirror; 16 = ds_swizzle (only LDS op); 32 = permlane32_swap (VALU).
// Every lane ends with the full 64-lane sum.
// ---------------------------------------------------------------------------
__device__ inline float bfly_dpp(float x, const int ctrl) {
    // NOTE: ctrl must be a literal at each call site (constant-folded).
    int r;
    switch (ctrl) {
        case 0xB1:  r = __builtin_amdgcn_update_dpp(0, __float_as_int(x), 0xB1,  0xF, 0xF, false); break;
        case 0x4E:  r = __builtin_amdgcn_update_dpp(0, __float_as_int(x), 0x4E,  0xF, 0xF, false); break;
        case 0x141: r = __builtin_amdgcn_update_dpp(0, __float_as_int(x), 0x141, 0xF, 0xF, false); break;
        default:    r = __builtin_amdgcn_update_dpp(0, __float_as_int(x), 0x140, 0xF, 0xF, false); break;
    }
    return x + __int_as_float(r);
}
__device__ inline float wave_sum(float x) {
    x = bfly_dpp(x, 0xB1);                                   // xor 1 (quad_perm [1,0,3,2])
    x = bfly_dpp(x, 0x4E);                                   // xor 2 (quad_perm [2,3,0,1])
    x = bfly_dpp(x, 0x141);                                  // xor 7 (row_half_mirror)
    x = bfly_dpp(x, 0x140);                                  // xor 15 (row_mirror)
    x += __int_as_float(__builtin_amdgcn_ds_swizzle(__float_as_int(x), 0x401F)); // xor 16
    {                                                        // xor 32 via permlane32_swap
        auto pr = __builtin_amdgcn_permlane32_swap(__float_as_int(x), __float_as_int(x), false, false);
        int2 q; __builtin_memcpy(&q, &pr, 8);
        x = __int_as_float(q.x) + __int_as_float(q.y);
    }
    return x;
}

// ---------------------------------------------------------------------------
// batched exact fp32 repair, token-parallel, ZERO weight-LDS:
//   grid = 1024 WGs = 256 row-groups (rg) x 4 token-groups (tg).
//   Each LANE holds its 16-element slice of the WG's 4 Qw rows + 4 Kw rows in
//   VGPRs (32 float4 = 128 regs, loaded once). Per token: 8 global x-loads,
//   128 FMAs, and a mostly-VALU wave reduce (1 ds_swizzle per value).
//   vs round-3: 80 LDS-pipe ops/iter -> 8 (the LDS pipe was the bottleneck).
// ---------------------------------------------------------------------------
__global__ __launch_bounds__(256, 2)
void repair_kernel(const float* __restrict__ X,
                   const float* __restrict__ Qw,
                   const float* __restrict__ Kw,
                   const int* __restrict__ flags,
                   float* __restrict__ parts)
{
    const int tid  = threadIdx.x;
    const int lane = tid & 63;
    const int wv   = tid >> 6;
    const int rg   = blockIdx.x & 255;
    const int tg   = blockIdx.x >> 8;              // 0..3
    const int e0   = rg << 2;

    // ---- weights into registers: 4 Q-rows + 4 K-rows, 16 elems/lane ----
    float4 wq[4][4], wk[4][4];
    #pragma unroll
    for (int r = 0; r < 4; ++r) {
        #pragma unroll
        for (int jj = 0; jj < 4; ++jj) {
            const int idx = (jj*64 + lane)*4;      // coalesced across lanes
            wq[r][jj] = *(const float4*)&Qw[(size_t)(e0 + r)*Dc + idx];
            wk[r][jj] = *(const float4*)&Kw[(size_t)(e0 + r)*Dc + idx];
        }
    }

    const int count = min(flags[0], 2048);
    for (int fi = tg*4 + wv; fi < count; fi += 16) {
        const int t = flags[1 + fi];
        const float* x0 = &X[(size_t)t*Dc];
        const float* x1 = x0 + Dc;                 // t+1 (flag excludes l=L-1)
        float s0[4] = {0.f,0.f,0.f,0.f}, s1[4] = {0.f,0.f,0.f,0.f};
        #pragma unroll
        for (int jj = 0; jj < 4; ++jj) {
            const int idx = (jj*64 + lane)*4;
            const float4 a0 = *(const float4*)&x0[idx];
            const float4 a1 = *(const float4*)&x1[idx];
            #pragma unroll
            for (int r = 0; r < 4; ++r) {
                s0[r] += wq[r][jj].x*a0.x + wq[r][jj].y*a0.y + wq[r][jj].z*a0.z + wq[r][jj].w*a0.w;
                s1[r] += wk[r][jj].x*a1.x + wk[r][jj].y*a1.y + wk[r][jj].z*a1.z + wk[r][jj].w*a1.w;
            }
        }
        #pragma unroll
        for (int r = 0; r < 4; ++r) {
            s0[r] = wave_sum(s0[r]);
            s1[r] = wave_sum(s1[r]);
        }
        if (lane == 0) {
            float d = 0.f, qq = 0.f, kk = 0.f;
            #pragma unroll
            for (int r = 0; r < 4; ++r) {
                d  += s0[r]*s1[r];
                qq += s0[r]*s0[r];
                kk += s1[r]*s1[r];
            }
            atomicAdd(&parts[t],          d);
            atomicAdd(&parts[Mtot + t],   qq);
            atomicAdd(&parts[2*Mtot + t], kk);
        }
    }
}

__global__ __launch_bounds__(256)
void repair_fin_kernel(const float* __restrict__ parts,
                       const int* __restrict__ flags,
                       float* __restrict__ cosv)
{
    const int i = blockIdx.x*256 + threadIdx.x;
    const int count = min(flags[0], 2048);
    if (i < count) {
        const int t = flags[1 + i];
        const float dot = parts[t];
        const float qn  = parts[Mtot + t];
        const float kn  = parts[2*Mtot + t];
        cosv[t] = dot / (fmaxf(sqrtf(qn), 1e-12f) * fmaxf(sqrtf(kn), 1e-12f));
    }
}

// ---------------------------------------------------------------------------
// EMA scan — branchless; NSEG=128 (SEGLEN=32).
// ---------------------------------------------------------------------------
__device__ inline void build_seg_coefs(const float* __restrict__ cosv,
                                       int b, int l0,
                                       float* decA, float* wB)
{
    const int tid = threadIdx.x;
    if (tid < SEGLEN) {
        const int l = l0 + tid;
        float p;
        if (l == 0) {
            p = 1.f;
        } else {
            const float c = cosv[b*Lc + l - 1];
            p = fminf(fmaxf((1.f - c) * 0.5f, 0.f), 1.f);
        }
        const bool m = p > 0.5f;
        decA[tid] = m ? (1.f - p) : 1.f;
        wB[tid]   = m ? p : 0.f;
    }
    __syncthreads();
}

__global__ __launch_bounds__(256)
void seg_pass1_kernel(const float* __restrict__ X,
                      const float* __restrict__ cosv,
                      float* __restrict__ Aseg,
                      float* __restrict__ Bseg)
{
    __shared__ float decA[SEGLEN];
    __shared__ float wB[SEGLEN];
    const int tid = threadIdx.x;
    const int b = blockIdx.x >> 7;
    const int s = blockIdx.x & 127;
    const int l0 = s * SEGLEN;
    build_seg_coefs(cosv, b, l0, decA, wB);

    float4 st = make_float4(0.f, 0.f, 0.f, 0.f);
    float A = 1.f;
    const float* xb = X + (size_t)(b*Lc + l0)*Dc + tid*4;
    #pragma unroll 8
    for (int i = 0; i < SEGLEN; i++) {
        const float a = decA[i], w = wB[i];
        const float4 xv = *(const float4*)(xb + (size_t)i*Dc);
        st.x = a*st.x + w*xv.x;
        st.y = a*st.y + w*xv.y;
        st.z = a*st.z + w*xv.z;
        st.w = a*st.w + w*xv.w;
        A *= a;
    }
    *(float4*)&Bseg[(size_t)blockIdx.x*Dc + tid*4] = st;
    if (tid == 0) Aseg[blockIdx.x] = A;
}

__global__ __launch_bounds__(256)
void seg_combine_kernel(const float* __restrict__ Aseg,
                        const float* __restrict__ Bseg,
                        const float* __restrict__ init_state,
                        float* __restrict__ carry)
{
    const int tid = threadIdx.x;
    const int b  = blockIdx.x >> 2;
    const int d  = ((blockIdx.x & 3) << 8) + tid;
    float c = init_state[(size_t)b*Dc + d];
    for (int s = 0; s < NSEG; s++) {
        const size_t idx = (size_t)(b*NSEG + s);
        carry[idx*Dc + d] = c;
        c = Aseg[idx]*c + Bseg[idx*Dc + d];
    }
}

__global__ __launch_bounds__(256)
void seg_pass2_kernel(const float* __restrict__ X,
                      const float* __restrict__ RES,
                      const float* __restrict__ cosv,
                      const float* __restrict__ carry,
                      float* __restrict__ OUT)
{
    __shared__ float decA[SEGLEN];
    __shared__ float wB[SEGLEN];
    const int tid = threadIdx.x;
    const int b = blockIdx.x >> 7;
    const int s = blockIdx.x & 127;
    const int l0 = s * SEGLEN;
    build_seg_coefs(cosv, b, l0, decA, wB);

    float4 st = *(const float4*)&carry[(size_t)blockIdx.x*Dc + tid*4];
    const size_t base = (size_t)(b*Lc + l0)*Dc + tid*4;
    const float* xb = X   + base;
    const float* rb = RES + base;
    float*       ob = OUT + base;
    #pragma unroll 4
    for (int i = 0; i < SEGLEN; i++) {
        const float a = decA[i], w = wB[i];
        const float4 xv = *(const float4*)(xb + (size_t)i*Dc);
        const float4 rv = *(const float4*)(rb + (size_t)i*Dc);
        st.x = a*st.x + w*xv.x;
        st.y = a*st.y + w*xv.y;
        st.z = a*st.z + w*xv.z;
        st.w = a*st.w + w*xv.w;
        float4 ov;
        ov.x = rv.x + st.x;
        ov.y = rv.y + st.y;
        ov.z = rv.z + st.z;
        ov.w = rv.w + st.w;
        *(float4*)(ob + (size_t)i*Dc) = ov;
    }
}

// ---------------------------------------------------------------------------
extern "C" void kernel_launch(void* const* d_in, const int* in_sizes, int n_in,
                              void* d_out, int out_size, void* d_ws, size_t ws_size,
                              hipStream_t stream)
{
    const float* X    = (const float*)d_in[0];
    const float* RES  = (const float*)d_in[1];
    const float* QW   = (const float*)d_in[2];
    const float* KW   = (const float*)d_in[3];
    const float* INIT = (const float*)d_in[4];
    float* OUT = (float*)d_out;

    char* ws = (char*)d_ws;
    us*    Qh    = (us*)   (ws + OFF_QH);
    us*    Kh    = (us*)   (ws + OFF_KH);
    us*    Xbf   = (us*)   (ws + OFF_XBF);
    float* parts = (float*)(ws + OFF_PARTS);
    int*   flags = (int*)  (ws + OFF_FLAGS);
    float* cosv  = (float*)(ws + OFF_COSV);
    float* Aseg  = (float*)(ws + OFF_ASEG);
    float* Bseg  = (float*)(ws + OFF_BSEG);
    float* carry = (float*)(ws + OFF_CARRY);

    prep_kernel      <<<2752, 256, 0, stream>>>(QW, KW, X, Qh, Kh, Xbf, parts, flags);
    gemm_cos_kernel  <<<1024, 256, 0, stream>>>(Xbf, Qh, Kh, parts);
    cos_fin_kernel   <<<64,   256, 0, stream>>>(parts, cosv, flags);
    repair_kernel    <<<1024, 256, 0, stream>>>(X, QW, KW, flags, parts);
    repair_fin_kernel<<<8,    256, 0, stream>>>(parts, flags, cosv);
    seg_pass1_kernel  <<<Bc*NSEG, 256, 0, stream>>>(X, cosv, Aseg, Bseg);
    seg_combine_kernel<<<Bc*4,    256, 0, stream>>>(Aseg, Bseg, INIT, carry);
    seg_pass2_kernel  <<<Bc*NSEG, 256, 0, stream>>>(X, RES, cosv, carry, OUT);
}

// Round 5
// 426.238 us; speedup vs baseline: 1.0798x; 1.0798x over previous
//
#include <hip/hip_runtime.h>
#include <math.h>

#define Bc 4
#define Lc 4096
#define Dc 1024
#define Mtot (Bc*Lc)          // 16384 flattened tokens
#define NSEG 128
#define SEGLEN (Lc/NSEG)      // 32

typedef __attribute__((ext_vector_type(8))) short short8;
typedef __attribute__((ext_vector_type(4))) float floatx4;
typedef unsigned short us;

// ---- workspace layout (bytes) — total ~48.5 MB ----
#define OFF_QH    ((size_t)0)          // 1024x1024 bf16
#define OFF_KH    ((size_t)2097152)
#define OFF_XBF   ((size_t)4194304)    // Mtot x 1024 bf16 (32 MB)
#define OFF_PARTS ((size_t)37748736)   // 3*Mtot f32 (dot,qn,kn)
#define OFF_FLAGS ((size_t)37945344)   // int count + 2048 idx (8448 B)
#define OFF_COSV  ((size_t)37953792)   // Mtot f32
#define OFF_ASEG  ((size_t)38019328)   // Bc*NSEG f32 (2 KB)
#define OFF_BSEG  ((size_t)38021376)   // Bc*NSEG*Dc f32 (2 MB)
#define OFF_CARRY ((size_t)40118528)   // 2 MB
#define OFF_PBUF  ((size_t)42215680)   // 2048 x 3 x 256 f32 (6.3 MB) repair partials

// ---------------------------------------------------------------------------
__device__ inline us f2bf(float x) {
    unsigned int u = __float_as_uint(x);
    u += 0x7FFFu + ((u >> 16) & 1u);
    return (us)(u >> 16);
}

// ---------------------------------------------------------------------------
// prep: Qw/Kw fp32 -> bf16, X fp32 -> bf16 (one-shot, hoisted out of GEMM),
// zero parts + flags.
// ---------------------------------------------------------------------------
__global__ __launch_bounds__(256)
void prep_kernel(const float* __restrict__ Qw, const float* __restrict__ Kw,
                 const float* __restrict__ X,
                 us* __restrict__ Qh, us* __restrict__ Kh, us* __restrict__ Xbf,
                 float* __restrict__ parts, int* __restrict__ flags)
{
    const int bid = blockIdx.x, tid = threadIdx.x;
    if (bid < 512) {
        const float* W = (bid < 256) ? Qw : Kw;
        us* Wh = (bid < 256) ? Qh : Kh;
        const int lb = bid & 255;
        #pragma unroll
        for (int k = 0; k < 4; ++k) {
            const size_t e4 = (size_t)lb*1024 + k*256 + tid;
            const float4 v = *(const float4*)&W[e4*4];
            ushort4 h;
            h.x = f2bf(v.x); h.y = f2bf(v.y); h.z = f2bf(v.z); h.w = f2bf(v.w);
            *(ushort4*)&Wh[e4*4] = h;
        }
    } else if (bid < 704) {
        const int idx = (bid - 512)*256 + tid;
        if (idx < 3*Mtot) parts[idx] = 0.f;
        if (idx == 0) flags[0] = 0;
    } else {
        const int xb = bid - 704;                   // 0..2047
        const float4* src = (const float4*)X;
        ushort4* dst = (ushort4*)Xbf;
        #pragma unroll
        for (int j = 0; j < 8; ++j) {
            const size_t f = (size_t)xb*2048 + j*256 + tid;
            const float4 v = src[f];
            ushort4 h;
            h.x = f2bf(v.x); h.y = f2bf(v.y); h.z = f2bf(v.z); h.w = f2bf(v.w);
            dst[f] = h;
        }
    }
}

// ---------------------------------------------------------------------------
// Single-product bf16 MFMA GEMM: q_t = Qw.x_t, k'_t = Kw.x_{t+1}.
// A (X tile, 129x32, +1-row halo) AND B (Q,K weight tiles) both staged via
// global_load_lds from pre-converted bf16, with pre-swizzled per-lane source
// addresses (granule-XOR (row>>1)&3) -> linear LDS dest, conflict-free reads.
// Per-lane staging pointers precomputed, marched +64B/chunk: ~no in-loop VALU.
// Tiles: 128(M) x 128(N), BK=32. LDS = (516 + 1024) granules = 24,640 B.
// ---------------------------------------------------------------------------
#define AS1C const __attribute__((address_space(1))) void*
#define AS3P __attribute__((address_space(3))) void*

__global__ __launch_bounds__(256, 2)
void gemm_cos_kernel(const us* __restrict__ Xbf,
                     const us* __restrict__ Qh,
                     const us* __restrict__ Kh,
                     float* __restrict__ parts)
{
    __shared__ __align__(16) us lds[12320];
    us* AsH = lds;                 // 516 granules: (row,c) at row*32 + c*8
    us* Bs  = lds + 4128;          // 1024 granules: Q tile then K tile

    const int tid  = threadIdx.x;
    const int lane = tid & 63;
    const int wv   = tid >> 6;
    const int wm   = wv >> 1;
    const int wn   = wv & 1;
    // XCD-aware swizzle (1024 % 8 == 0 -> bijective)
    const int swz  = ((blockIdx.x & 7) << 7) | (blockIdx.x >> 3);
    const int bm   = swz >> 3;
    const int bn   = swz & 7;
    const int t0   = bm * 128;
    const int nb   = bn * 128;

    floatx4 accq[4][4], acck[4][4];
    const floatx4 zz = {0.f, 0.f, 0.f, 0.f};
    #pragma unroll
    for (int i = 0; i < 4; i++)
        #pragma unroll
        for (int j = 0; j < 4; j++) { accq[i][j] = zz; acck[i][j] = zz; }

    // ---- staging source pointers (per-lane, pre-swizzled), marched /chunk ----
    // A granule g: row=g>>2, c=g&3; source column-granule = c ^ ((row>>1)&3)
    const int r0 = tid >> 2, c0 = tid & 3;
    const int r1 = r0 + 64;
    const us* pA0 = Xbf + (size_t)(t0 + r0)*Dc + ((c0 ^ ((r0 >> 1) & 3)) << 3);
    const us* pA1 = Xbf + (size_t)(t0 + r1)*Dc + ((c0 ^ ((r1 >> 1) & 3)) << 3);
    int ta2 = t0 + 128; if (ta2 >= Mtot) ta2 = Mtot - 1;   // halo row clamp
    const us* pA2 = Xbf + (size_t)ta2*Dc + ((tid & 3) << 3); // (128>>1)&3 == 0
    const us* pB[4];
    #pragma unroll
    for (int it = 0; it < 4; ++it) {
        const int g   = it*256 + tid;
        const us* wbase = (g & 512) ? Kh : Qh;
        const int gg  = g & 511;
        const int row = gg >> 2;
        const int sl  = (gg & 3) ^ ((row >> 1) & 3);
        pB[it] = wbase + (size_t)(nb + row)*Dc + (sl << 3);
    }

    const int lrow = lane & 15;
    const int lg   = lane >> 4;    // k-granule 0..3 (8 shorts each)

    for (int ch = 0; ch < 32; ++ch) {
        // ---- stage A + B via global_load_lds (7 issues/thread) ----
        __builtin_amdgcn_global_load_lds((AS1C)pA0, (AS3P)(AsH + tid*8),       16, 0, 0);
        __builtin_amdgcn_global_load_lds((AS1C)pA1, (AS3P)(AsH + (tid+256)*8), 16, 0, 0);
        if (tid < 4)
            __builtin_amdgcn_global_load_lds((AS1C)pA2, (AS3P)(AsH + (tid+512)*8), 16, 0, 0);
        #pragma unroll
        for (int it = 0; it < 4; ++it)
            __builtin_amdgcn_global_load_lds((AS1C)pB[it], (AS3P)(Bs + (it*256 + tid)*8), 16, 0, 0);
        pA0 += 32; pA1 += 32; pA2 += 32;
        pB[0] += 32; pB[1] += 32; pB[2] += 32; pB[3] += 32;
        __syncthreads();

        short8 aq[4], ak[4];
        #pragma unroll
        for (int i = 0; i < 4; ++i) {
            const int r  = wm*64 + i*16 + lrow;
            const int r1f = r + 1;
            aq[i] = *(const short8*)&AsH[r  *32 + ((lg ^ ((r   >> 1) & 3)) << 3)];
            ak[i] = *(const short8*)&AsH[r1f*32 + ((lg ^ ((r1f >> 1) & 3)) << 3)];
        }
        #pragma unroll
        for (int j = 0; j < 4; ++j) {
            const int rn = wn*64 + j*16 + lrow;
            const int bo = rn*32 + ((lg ^ ((rn >> 1) & 3)) << 3);
            const short8 fbq = *(const short8*)&Bs[bo];
            const short8 fbk = *(const short8*)&Bs[4096 + bo];
            #pragma unroll
            for (int i = 0; i < 4; ++i) {
                accq[i][j] = __builtin_amdgcn_mfma_f32_16x16x32_bf16(aq[i], fbq, accq[i][j], 0, 0, 0);
                acck[i][j] = __builtin_amdgcn_mfma_f32_16x16x32_bf16(ak[i], fbk, acck[i][j], 0, 0, 0);
            }
        }
        __syncthreads();
    }

    // ---- epilogue: per-row dot/qn/kn over this WG's 128 cols, then atomics ----
    #pragma unroll
    for (int i = 0; i < 4; ++i) {
        #pragma unroll
        for (int reg = 0; reg < 4; ++reg) {
            float d = 0.f, qq = 0.f, kk = 0.f;
            #pragma unroll
            for (int j = 0; j < 4; ++j) {
                const float qv = accq[i][j][reg];
                const float kv = acck[i][j][reg];
                d  += qv * kv;
                qq += qv * qv;
                kk += kv * kv;
            }
            #pragma unroll
            for (int m = 1; m <= 8; m <<= 1) {
                d  += __shfl_xor(d,  m);
                qq += __shfl_xor(qq, m);
                kk += __shfl_xor(kk, m);
            }
            if ((lane & 15) == 0) {
                const int row = t0 + wm*64 + i*16 + ((lane >> 4) << 2) + reg;
                atomicAdd(&parts[row],          d);
                atomicAdd(&parts[Mtot + row],   qq);
                atomicAdd(&parts[2*Mtot + row], kk);
            }
        }
    }
}

// ---------------------------------------------------------------------------
// finalize cos + flag near-boundary tokens (|cos| < 1.2e-3 ~= 12 sigma of the
// single-product bf16 error). Repair now writes contention-free partials, so
// flagged parts need NOT be zeroed.
// ---------------------------------------------------------------------------
__global__ __launch_bounds__(256)
void cos_fin_kernel(float* __restrict__ parts,
                    float* __restrict__ cosv,
                    int* __restrict__ flags)
{
    const int t = blockIdx.x*256 + threadIdx.x;
    if (t >= Mtot) return;
    const float dot = parts[t];
    const float qn  = parts[Mtot + t];
    const float kn  = parts[2*Mtot + t];
    const float c = dot / (fmaxf(sqrtf(qn), 1e-12f) * fmaxf(sqrtf(kn), 1e-12f));
    cosv[t] = c;
    if (fabsf(c) < 1.2e-3f && (t & (Lc-1)) != (Lc-1)) {
        const int idx = atomicAdd(flags, 1);
        if (idx < 2048) flags[1 + idx] = t;
    }
}

// ---------------------------------------------------------------------------
// Wave-wide f32 sum with minimal LDS-pipe use: butterfly masks {1,2,7,15,16,32}
// (span all 6 lane bits). 1,2 = DPP quad_perm; 7,15 = DPP row_half_mirror /
// row_mirror; 16 = ds_swizzle (only LDS op); 32 = permlane32_swap (VALU).
// ---------------------------------------------------------------------------
__device__ inline float bfly_dpp(float x, const int ctrl) {
    int r;
    switch (ctrl) {
        case 0xB1:  r = __builtin_amdgcn_update_dpp(0, __float_as_int(x), 0xB1,  0xF, 0xF, false); break;
        case 0x4E:  r = __builtin_amdgcn_update_dpp(0, __float_as_int(x), 0x4E,  0xF, 0xF, false); break;
        case 0x141: r = __builtin_amdgcn_update_dpp(0, __float_as_int(x), 0x141, 0xF, 0xF, false); break;
        default:    r = __builtin_amdgcn_update_dpp(0, __float_as_int(x), 0x140, 0xF, 0xF, false); break;
    }
    return x + __int_as_float(r);
}
__device__ inline float wave_sum(float x) {
    x = bfly_dpp(x, 0xB1);                                   // xor 1
    x = bfly_dpp(x, 0x4E);                                   // xor 2
    x = bfly_dpp(x, 0x141);                                  // xor 7
    x = bfly_dpp(x, 0x140);                                  // xor 15
    x += __int_as_float(__builtin_amdgcn_ds_swizzle(__float_as_int(x), 0x401F)); // xor 16
    {                                                        // xor 32 via permlane32_swap
        auto pr = __builtin_amdgcn_permlane32_swap(__float_as_int(x), __float_as_int(x), false, false);
        int2 q; __builtin_memcpy(&q, &pr, 8);
        x = __int_as_float(q.x) + __int_as_float(q.y);
    }
    return x;
}

// keep a float4's components alive in VGPRs (defeats load rematerialization)
#define PIN4(v) asm volatile("" : "+v"(v.x), "+v"(v.y), "+v"(v.z), "+v"(v.w))

// ---------------------------------------------------------------------------
// batched exact fp32 repair, token-parallel, weights PINNED in VGPRs:
//   grid = 1024 WGs = 256 row-groups (rg) x 4 token-groups (tg).
//   Each lane holds its 16-elem slice of 4 Qw + 4 Kw rows (32 float4 = 128
//   VGPRs, loaded once, PIN4'd so the compiler cannot sink the loads into the
//   loop — round-4 failure: VGPR_Count=84 proved weights were re-read/iter).
//   Per token: 8 x-loads + 128 FMAs + wave reduce; lane0 STORES (d,qq,kk) to
//   a unique pbuf slot [fi][c][rg] — zero atomic contention.
// ---------------------------------------------------------------------------
__global__ __launch_bounds__(256, 2)
void repair_kernel(const float* __restrict__ X,
                   const float* __restrict__ Qw,
                   const float* __restrict__ Kw,
                   const int* __restrict__ flags,
                   float* __restrict__ pbuf)
{
    const int tid  = threadIdx.x;
    const int lane = tid & 63;
    const int wv   = tid >> 6;
    const int rg   = blockIdx.x & 255;
    const int tg   = blockIdx.x >> 8;              // 0..3
    const int e0   = rg << 2;

    // ---- weights into registers: 4 Q-rows + 4 K-rows, 16 elems/lane ----
    float4 wq[4][4], wk[4][4];
    #pragma unroll
    for (int r = 0; r < 4; ++r) {
        #pragma unroll
        for (int jj = 0; jj < 4; ++jj) {
            const int idx = (jj*64 + lane)*4;      // coalesced across lanes
            wq[r][jj] = *(const float4*)&Qw[(size_t)(e0 + r)*Dc + idx];
            wk[r][jj] = *(const float4*)&Kw[(size_t)(e0 + r)*Dc + idx];
            PIN4(wq[r][jj]);
            PIN4(wk[r][jj]);
        }
    }

    const int count = min(flags[0], 2048);
    for (int fi = tg*4 + wv; fi < count; fi += 16) {
        const int t = flags[1 + fi];
        const float* x0 = &X[(size_t)t*Dc];
        const float* x1 = x0 + Dc;                 // t+1 (flag excludes l=L-1)
        float s0[4] = {0.f,0.f,0.f,0.f}, s1[4] = {0.f,0.f,0.f,0.f};
        #pragma unroll
        for (int jj = 0; jj < 4; ++jj) {
            const int idx = (jj*64 + lane)*4;
            const float4 a0 = *(const float4*)&x0[idx];
            const float4 a1 = *(const float4*)&x1[idx];
            #pragma unroll
            for (int r = 0; r < 4; ++r) {
                s0[r] += wq[r][jj].x*a0.x + wq[r][jj].y*a0.y + wq[r][jj].z*a0.z + wq[r][jj].w*a0.w;
                s1[r] += wk[r][jj].x*a1.x + wk[r][jj].y*a1.y + wk[r][jj].z*a1.z + wk[r][jj].w*a1.w;
            }
        }
        #pragma unroll
        for (int r = 0; r < 4; ++r) {
            s0[r] = wave_sum(s0[r]);
            s1[r] = wave_sum(s1[r]);
        }
        if (lane == 0) {
            float d = 0.f, qq = 0.f, kk = 0.f;
            #pragma unroll
            for (int r = 0; r < 4; ++r) {
                d  += s0[r]*s1[r];
                qq += s0[r]*s0[r];
                kk += s1[r]*s1[r];
            }
            float* pb = pbuf + (size_t)fi*768 + rg;
            pb[0]   = d;
            pb[256] = qq;
            pb[512] = kk;
        }
    }
}

// ---------------------------------------------------------------------------
// repair finalize: one wave per flagged token sums 256 partials per component
// (coalesced float4 reads) and writes the exact cos.
// ---------------------------------------------------------------------------
__global__ __launch_bounds__(256)
void repair_fin_kernel(const float* __restrict__ pbuf,
                       const int* __restrict__ flags,
                       float* __restrict__ cosv)
{
    const int lane = threadIdx.x & 63;
    const int wv   = threadIdx.x >> 6;
    const int fi   = blockIdx.x*4 + wv;
    const int count = min(flags[0], 2048);
    if (fi >= count) return;
    float s[3];
    #pragma unroll
    for (int c = 0; c < 3; ++c) {
        const float4 v = *(const float4*)&pbuf[(size_t)fi*768 + c*256 + lane*4];
        s[c] = wave_sum(v.x + v.y + v.z + v.w);
    }
    if (lane == 0) {
        const int t = flags[1 + fi];
        cosv[t] = s[0] / (fmaxf(sqrtf(s[1]), 1e-12f) * fmaxf(sqrtf(s[2]), 1e-12f));
    }
}

// ---------------------------------------------------------------------------
// EMA scan — branchless; NSEG=128 (SEGLEN=32).
// ---------------------------------------------------------------------------
__device__ inline void build_seg_coefs(const float* __restrict__ cosv,
                                       int b, int l0,
                                       float* decA, float* wB)
{
    const int tid = threadIdx.x;
    if (tid < SEGLEN) {
        const int l = l0 + tid;
        float p;
        if (l == 0) {
            p = 1.f;
        } else {
            const float c = cosv[b*Lc + l - 1];
            p = fminf(fmaxf((1.f - c) * 0.5f, 0.f), 1.f);
        }
        const bool m = p > 0.5f;
        decA[tid] = m ? (1.f - p) : 1.f;
        wB[tid]   = m ? p : 0.f;
    }
    __syncthreads();
}

__global__ __launch_bounds__(256)
void seg_pass1_kernel(const float* __restrict__ X,
                      const float* __restrict__ cosv,
                      float* __restrict__ Aseg,
                      float* __restrict__ Bseg)
{
    __shared__ float decA[SEGLEN];
    __shared__ float wB[SEGLEN];
    const int tid = threadIdx.x;
    const int b = blockIdx.x >> 7;
    const int s = blockIdx.x & 127;
    const int l0 = s * SEGLEN;
    build_seg_coefs(cosv, b, l0, decA, wB);

    float4 st = make_float4(0.f, 0.f, 0.f, 0.f);
    float A = 1.f;
    const float* xb = X + (size_t)(b*Lc + l0)*Dc + tid*4;
    #pragma unroll 8
    for (int i = 0; i < SEGLEN; i++) {
        const float a = decA[i], w = wB[i];
        const float4 xv = *(const float4*)(xb + (size_t)i*Dc);
        st.x = a*st.x + w*xv.x;
        st.y = a*st.y + w*xv.y;
        st.z = a*st.z + w*xv.z;
        st.w = a*st.w + w*xv.w;
        A *= a;
    }
    *(float4*)&Bseg[(size_t)blockIdx.x*Dc + tid*4] = st;
    if (tid == 0) Aseg[blockIdx.x] = A;
}

__global__ __launch_bounds__(256)
void seg_combine_kernel(const float* __restrict__ Aseg,
                        const float* __restrict__ Bseg,
                        const float* __restrict__ init_state,
                        float* __restrict__ carry)
{
    const int tid = threadIdx.x;
    const int b  = blockIdx.x >> 2;
    const int d  = ((blockIdx.x & 3) << 8) + tid;
    float c = init_state[(size_t)b*Dc + d];
    for (int s = 0; s < NSEG; s++) {
        const size_t idx = (size_t)(b*NSEG + s);
        carry[idx*Dc + d] = c;
        c = Aseg[idx]*c + Bseg[idx*Dc + d];
    }
}

__global__ __launch_bounds__(256)
void seg_pass2_kernel(const float* __restrict__ X,
                      const float* __restrict__ RES,
                      const float* __restrict__ cosv,
                      const float* __restrict__ carry,
                      float* __restrict__ OUT)
{
    __shared__ float decA[SEGLEN];
    __shared__ float wB[SEGLEN];
    const int tid = threadIdx.x;
    const int b = blockIdx.x >> 7;
    const int s = blockIdx.x & 127;
    const int l0 = s * SEGLEN;
    build_seg_coefs(cosv, b, l0, decA, wB);

    float4 st = *(const float4*)&carry[(size_t)blockIdx.x*Dc + tid*4];
    const size_t base = (size_t)(b*Lc + l0)*Dc + tid*4;
    const float* xb = X   + base;
    const float* rb = RES + base;
    float*       ob = OUT + base;
    #pragma unroll 4
    for (int i = 0; i < SEGLEN; i++) {
        const float a = decA[i], w = wB[i];
        const float4 xv = *(const float4*)(xb + (size_t)i*Dc);
        const float4 rv = *(const float4*)(rb + (size_t)i*Dc);
        st.x = a*st.x + w*xv.x;
        st.y = a*st.y + w*xv.y;
        st.z = a*st.z + w*xv.z;
        st.w = a*st.w + w*xv.w;
        float4 ov;
        ov.x = rv.x + st.x;
        ov.y = rv.y + st.y;
        ov.z = rv.z + st.z;
        ov.w = rv.w + st.w;
        *(float4*)(ob + (size_t)i*Dc) = ov;
    }
}

// ---------------------------------------------------------------------------
extern "C" void kernel_launch(void* const* d_in, const int* in_sizes, int n_in,
                              void* d_out, int out_size, void* d_ws, size_t ws_size,
                              hipStream_t stream)
{
    const float* X    = (const float*)d_in[0];
    const float* RES  = (const float*)d_in[1];
    const float* QW   = (const float*)d_in[2];
    const float* KW   = (const float*)d_in[3];
    const float* INIT = (const float*)d_in[4];
    float* OUT = (float*)d_out;

    char* ws = (char*)d_ws;
    us*    Qh    = (us*)   (ws + OFF_QH);
    us*    Kh    = (us*)   (ws + OFF_KH);
    us*    Xbf   = (us*)   (ws + OFF_XBF);
    float* parts = (float*)(ws + OFF_PARTS);
    int*   flags = (int*)  (ws + OFF_FLAGS);
    float* cosv  = (float*)(ws + OFF_COSV);
    float* Aseg  = (float*)(ws + OFF_ASEG);
    float* Bseg  = (float*)(ws + OFF_BSEG);
    float* carry = (float*)(ws + OFF_CARRY);
    float* pbuf  = (float*)(ws + OFF_PBUF);

    prep_kernel      <<<2752, 256, 0, stream>>>(QW, KW, X, Qh, Kh, Xbf, parts, flags);
    gemm_cos_kernel  <<<1024, 256, 0, stream>>>(Xbf, Qh, Kh, parts);
    cos_fin_kernel   <<<64,   256, 0, stream>>>(parts, cosv, flags);
    repair_kernel    <<<1024, 256, 0, stream>>>(X, QW, KW, flags, pbuf);
    repair_fin_kernel<<<512,  256, 0, stream>>>(pbuf, flags, cosv);
    seg_pass1_kernel  <<<Bc*NSEG, 256, 0, stream>>>(X, cosv, Aseg, Bseg);
    seg_combine_kernel<<<Bc*4,    256, 0, stream>>>(Aseg, Bseg, INIT, carry);
    seg_pass2_kernel  <<<Bc*NSEG, 256, 0, stream>>>(X, RES, cosv, carry, OUT);
}

// Round 6
// 377.413 us; speedup vs baseline: 1.2195x; 1.1294x over previous
//
#include <hip/hip_runtime.h>
#include <math.h>

#define Bc 4
#define Lc 4096
#define Dc 1024
#define Mtot (Bc*Lc)          // 16384 flattened tokens
#define NSEG 128
#define SEGLEN (Lc/NSEG)      // 32

typedef __attribute__((ext_vector_type(8))) short short8;
typedef __attribute__((ext_vector_type(4))) float floatx4;
typedef unsigned short us;

// ---- workspace layout (bytes) — total ~46.4 MB ----
// GX*/P2 alias XBF (XBF dead after gemm_cos; gather runs after).
#define OFF_QH    ((size_t)0)          // 1024x1024 bf16
#define OFF_QL    ((size_t)2097152)
#define OFF_KH    ((size_t)4194304)
#define OFF_KL    ((size_t)6291456)
#define OFF_XBF   ((size_t)8388608)    // Mtot x 1024 bf16 (32 MB), ends 41943040
#define OFF_GX0H  ((size_t)8388608)    // 1024 x 1024 bf16 (2 MB) — alias XBF
#define OFF_GX0L  ((size_t)10485760)
#define OFF_GX1H  ((size_t)12582912)
#define OFF_GX1L  ((size_t)14680064)
#define OFF_P2    ((size_t)16777216)   // 3*1024 f32 (12 KB) — alias XBF
#define OFF_PARTS ((size_t)41943040)   // 3*Mtot f32
#define OFF_FLAGS ((size_t)42139648)   // int count + 1024 idx
#define OFF_COSV  ((size_t)42148096)   // Mtot f32
#define OFF_ASEG  ((size_t)42213632)   // Bc*NSEG f32 (2 KB)
#define OFF_BSEG  ((size_t)42215680)   // 2 MB
#define OFF_CARRY ((size_t)44312832)   // 2 MB, ends 46409984

// ---------------------------------------------------------------------------
__device__ inline us f2bf(float x) {
    unsigned int u = __float_as_uint(x);
    u += 0x7FFFu + ((u >> 16) & 1u);
    return (us)(u >> 16);
}
__device__ inline float bf2f(us h) {
    return __uint_as_float(((unsigned int)h) << 16);
}

// ---------------------------------------------------------------------------
// prep: Qw/Kw fp32 -> bf16 hi+lo, X fp32 -> bf16, zero parts + flags.
// ---------------------------------------------------------------------------
__global__ __launch_bounds__(256)
void prep_kernel(const float* __restrict__ Qw, const float* __restrict__ Kw,
                 const float* __restrict__ X,
                 us* __restrict__ Qh, us* __restrict__ Ql,
                 us* __restrict__ Kh, us* __restrict__ Kl,
                 us* __restrict__ Xbf,
                 float* __restrict__ parts, int* __restrict__ flags)
{
    const int bid = blockIdx.x, tid = threadIdx.x;
    if (bid < 512) {
        const float* W = (bid < 256) ? Qw : Kw;
        us* Wh = (bid < 256) ? Qh : Kh;
        us* Wl = (bid < 256) ? Ql : Kl;
        const int lb = bid & 255;
        #pragma unroll
        for (int k = 0; k < 4; ++k) {
            const size_t e4 = (size_t)lb*1024 + k*256 + tid;
            const float4 v = *(const float4*)&W[e4*4];
            ushort4 h, l;
            h.x = f2bf(v.x); l.x = f2bf(v.x - bf2f(h.x));
            h.y = f2bf(v.y); l.y = f2bf(v.y - bf2f(h.y));
            h.z = f2bf(v.z); l.z = f2bf(v.z - bf2f(h.z));
            h.w = f2bf(v.w); l.w = f2bf(v.w - bf2f(h.w));
            *(ushort4*)&Wh[e4*4] = h;
            *(ushort4*)&Wl[e4*4] = l;
        }
    } else if (bid < 704) {
        const int idx = (bid - 512)*256 + tid;
        if (idx < 3*Mtot) parts[idx] = 0.f;
        if (idx == 0) flags[0] = 0;
    } else {
        const int xb = bid - 704;                   // 0..2047
        const float4* src = (const float4*)X;
        ushort4* dst = (ushort4*)Xbf;
        #pragma unroll
        for (int j = 0; j < 8; ++j) {
            const size_t f = (size_t)xb*2048 + j*256 + tid;
            const float4 v = src[f];
            ushort4 h;
            h.x = f2bf(v.x); h.y = f2bf(v.y); h.z = f2bf(v.z); h.w = f2bf(v.w);
            dst[f] = h;
        }
    }
}

// ---------------------------------------------------------------------------
// Single-product bf16 MFMA GEMM: q_t = Qw.x_t, k'_t = Kw.x_{t+1}.
// (unchanged from round 3/5 — staging via global_load_lds, swizzled)
// ---------------------------------------------------------------------------
#define AS1C const __attribute__((address_space(1))) void*
#define AS3P __attribute__((address_space(3))) void*

__global__ __launch_bounds__(256, 2)
void gemm_cos_kernel(const us* __restrict__ Xbf,
                     const us* __restrict__ Qh,
                     const us* __restrict__ Kh,
                     float* __restrict__ parts)
{
    __shared__ __align__(16) us lds[12320];
    us* AsH = lds;                 // 516 granules: (row,c) at row*32 + c*8
    us* Bs  = lds + 4128;          // 1024 granules: Q tile then K tile

    const int tid  = threadIdx.x;
    const int lane = tid & 63;
    const int wv   = tid >> 6;
    const int wm   = wv >> 1;
    const int wn   = wv & 1;
    const int swz  = ((blockIdx.x & 7) << 7) | (blockIdx.x >> 3);
    const int bm   = swz >> 3;
    const int bn   = swz & 7;
    const int t0   = bm * 128;
    const int nb   = bn * 128;

    floatx4 accq[4][4], acck[4][4];
    const floatx4 zz = {0.f, 0.f, 0.f, 0.f};
    #pragma unroll
    for (int i = 0; i < 4; i++)
        #pragma unroll
        for (int j = 0; j < 4; j++) { accq[i][j] = zz; acck[i][j] = zz; }

    const int r0 = tid >> 2, c0 = tid & 3;
    const int r1 = r0 + 64;
    const us* pA0 = Xbf + (size_t)(t0 + r0)*Dc + ((c0 ^ ((r0 >> 1) & 3)) << 3);
    const us* pA1 = Xbf + (size_t)(t0 + r1)*Dc + ((c0 ^ ((r1 >> 1) & 3)) << 3);
    int ta2 = t0 + 128; if (ta2 >= Mtot) ta2 = Mtot - 1;
    const us* pA2 = Xbf + (size_t)ta2*Dc + ((tid & 3) << 3);
    const us* pB[4];
    #pragma unroll
    for (int it = 0; it < 4; ++it) {
        const int g   = it*256 + tid;
        const us* wbase = (g & 512) ? Kh : Qh;
        const int gg  = g & 511;
        const int row = gg >> 2;
        const int sl  = (gg & 3) ^ ((row >> 1) & 3);
        pB[it] = wbase + (size_t)(nb + row)*Dc + (sl << 3);
    }

    const int lrow = lane & 15;
    const int lg   = lane >> 4;

    for (int ch = 0; ch < 32; ++ch) {
        __builtin_amdgcn_global_load_lds((AS1C)pA0, (AS3P)(AsH + tid*8),       16, 0, 0);
        __builtin_amdgcn_global_load_lds((AS1C)pA1, (AS3P)(AsH + (tid+256)*8), 16, 0, 0);
        if (tid < 4)
            __builtin_amdgcn_global_load_lds((AS1C)pA2, (AS3P)(AsH + (tid+512)*8), 16, 0, 0);
        #pragma unroll
        for (int it = 0; it < 4; ++it)
            __builtin_amdgcn_global_load_lds((AS1C)pB[it], (AS3P)(Bs + (it*256 + tid)*8), 16, 0, 0);
        pA0 += 32; pA1 += 32; pA2 += 32;
        pB[0] += 32; pB[1] += 32; pB[2] += 32; pB[3] += 32;
        __syncthreads();

        short8 aq[4], ak[4];
        #pragma unroll
        for (int i = 0; i < 4; ++i) {
            const int r  = wm*64 + i*16 + lrow;
            const int r1f = r + 1;
            aq[i] = *(const short8*)&AsH[r  *32 + ((lg ^ ((r   >> 1) & 3)) << 3)];
            ak[i] = *(const short8*)&AsH[r1f*32 + ((lg ^ ((r1f >> 1) & 3)) << 3)];
        }
        #pragma unroll
        for (int j = 0; j < 4; ++j) {
            const int rn = wn*64 + j*16 + lrow;
            const int bo = rn*32 + ((lg ^ ((rn >> 1) & 3)) << 3);
            const short8 fbq = *(const short8*)&Bs[bo];
            const short8 fbk = *(const short8*)&Bs[4096 + bo];
            #pragma unroll
            for (int i = 0; i < 4; ++i) {
                accq[i][j] = __builtin_amdgcn_mfma_f32_16x16x32_bf16(aq[i], fbq, accq[i][j], 0, 0, 0);
                acck[i][j] = __builtin_amdgcn_mfma_f32_16x16x32_bf16(ak[i], fbk, acck[i][j], 0, 0, 0);
            }
        }
        __syncthreads();
    }

    #pragma unroll
    for (int i = 0; i < 4; ++i) {
        #pragma unroll
        for (int reg = 0; reg < 4; ++reg) {
            float d = 0.f, qq = 0.f, kk = 0.f;
            #pragma unroll
            for (int j = 0; j < 4; ++j) {
                const float qv = accq[i][j][reg];
                const float kv = acck[i][j][reg];
                d  += qv * kv;
                qq += qv * qv;
                kk += kv * kv;
            }
            #pragma unroll
            for (int m = 1; m <= 8; m <<= 1) {
                d  += __shfl_xor(d,  m);
                qq += __shfl_xor(qq, m);
                kk += __shfl_xor(kk, m);
            }
            if ((lane & 15) == 0) {
                const int row = t0 + wm*64 + i*16 + ((lane >> 4) << 2) + reg;
                atomicAdd(&parts[row],          d);
                atomicAdd(&parts[Mtot + row],   qq);
                atomicAdd(&parts[2*Mtot + row], kk);
            }
        }
    }
}

// ---------------------------------------------------------------------------
// finalize cos + flag near-boundary tokens (|cos| < 1.2e-3 ~= 12 sigma of the
// single-product bf16 error). Also zeroes parts2 (safe here: Xbf alias is dead
// after gemm_cos, and this runs before repair).
// ---------------------------------------------------------------------------
__global__ __launch_bounds__(256)
void cos_fin_kernel(const float* __restrict__ parts,
                    float* __restrict__ cosv,
                    int* __restrict__ flags,
                    float* __restrict__ parts2)
{
    const int t = blockIdx.x*256 + threadIdx.x;
    if (t >= Mtot) return;
    if (t < 3072) parts2[t] = 0.f;
    const float dot = parts[t];
    const float qn  = parts[Mtot + t];
    const float kn  = parts[2*Mtot + t];
    const float c = dot / (fmaxf(sqrtf(qn), 1e-12f) * fmaxf(sqrtf(kn), 1e-12f));
    cosv[t] = c;
    if (fabsf(c) < 1.2e-3f && (t & (Lc-1)) != (Lc-1)) {
        const int idx = atomicAdd(flags, 1);
        if (idx < 1024) flags[1 + idx] = t;
    }
}

// ---------------------------------------------------------------------------
// gather: pack flagged x_t / x_{t+1} rows into dense hi/lo bf16 matrices.
// One WG per flagged token; each row read exactly ONCE (vs 256x in round 5).
// ---------------------------------------------------------------------------
__global__ __launch_bounds__(256)
void gather_kernel(const float* __restrict__ X,
                   const int* __restrict__ flags,
                   us* __restrict__ GX0H, us* __restrict__ GX0L,
                   us* __restrict__ GX1H, us* __restrict__ GX1L)
{
    const int fi = blockIdx.x;
    const int count = min(flags[0], 1024);
    if (fi >= count) return;
    const int t = flags[1 + fi];
    const int tid = threadIdx.x;
    const size_t o = (size_t)fi*Dc + tid*4;
    const float4 v0 = *(const float4*)&X[(size_t)t*Dc + tid*4];
    const float4 v1 = *(const float4*)&X[(size_t)(t+1)*Dc + tid*4];
    ushort4 h, l;
    h.x = f2bf(v0.x); l.x = f2bf(v0.x - bf2f(h.x));
    h.y = f2bf(v0.y); l.y = f2bf(v0.y - bf2f(h.y));
    h.z = f2bf(v0.z); l.z = f2bf(v0.z - bf2f(h.z));
    h.w = f2bf(v0.w); l.w = f2bf(v0.w - bf2f(h.w));
    *(ushort4*)&GX0H[o] = h; *(ushort4*)&GX0L[o] = l;
    h.x = f2bf(v1.x); l.x = f2bf(v1.x - bf2f(h.x));
    h.y = f2bf(v1.y); l.y = f2bf(v1.y - bf2f(h.y));
    h.z = f2bf(v1.z); l.z = f2bf(v1.z - bf2f(h.z));
    h.w = f2bf(v1.w); l.w = f2bf(v1.w - bf2f(h.w));
    *(ushort4*)&GX1H[o] = h; *(ushort4*)&GX1L[o] = l;
}

// ---------------------------------------------------------------------------
// repair GEMM: 3-product hi/lo bf16 emulation (xh*wh + xh*wl + xl*wh,
// error ~1e-5 << 1.2e-3 threshold). M = gathered flagged rows (<=1024),
// N = 1024 weight rows, K = 1024. Grid 64 = 8 bm x 8 bn, 128x128 tiles, BK=32.
// LDS: 8 tiles x 128 rows x 40-short padded stride (conflict-free b128 reads),
// reg-staged. Per-row dot/qn/kn partials -> atomics into parts2[3][1024].
// Replaces the serial broadcast repair (1 GB cache traffic -> ~12 MB).
// ---------------------------------------------------------------------------
__global__ __launch_bounds__(256, 1)
void repair_gemm_kernel(const us* __restrict__ GX0H, const us* __restrict__ GX0L,
                        const us* __restrict__ GX1H, const us* __restrict__ GX1L,
                        const us* __restrict__ Qh, const us* __restrict__ Ql,
                        const us* __restrict__ Kh, const us* __restrict__ Kl,
                        const int* __restrict__ flags,
                        float* __restrict__ parts2)
{
    __shared__ __align__(16) us lds[40960];        // 8 tiles x 5120 shorts (81,920 B)

    const int count = min(flags[0], 1024);
    const int bm = blockIdx.x >> 3;
    const int bn = blockIdx.x & 7;
    if (bm * 128 >= count) return;                 // WG-uniform early exit

    const int tid  = threadIdx.x;
    const int lane = tid & 63;
    const int wv   = tid >> 6;
    const int wm   = wv >> 1;
    const int wn   = wv & 1;
    const int lrow = lane & 15;
    const int lg   = lane >> 4;

    const us* srcs[8];
    const size_t fb = (size_t)bm*128*Dc;
    const size_t nbb = (size_t)bn*128*Dc;
    srcs[0] = GX0H + fb; srcs[1] = GX0L + fb;
    srcs[2] = GX1H + fb; srcs[3] = GX1L + fb;
    srcs[4] = Qh + nbb;  srcs[5] = Ql + nbb;
    srcs[6] = Kh + nbb;  srcs[7] = Kl + nbb;

    floatx4 accq[4][4], acck[4][4];
    const floatx4 zz = {0.f, 0.f, 0.f, 0.f};
    #pragma unroll
    for (int i = 0; i < 4; i++)
        #pragma unroll
        for (int j = 0; j < 4; j++) { accq[i][j] = zz; acck[i][j] = zz; }

    for (int ch = 0; ch < 32; ++ch) {
        const int k0 = ch << 5;
        // ---- reg-stage 8 tiles: 16 x (16B load + ds_write) per thread ----
        #pragma unroll
        for (int q = 0; q < 16; ++q) {
            const int tile = q >> 1;
            const int idx  = ((q & 1) << 8) + tid;   // 0..511
            const int row  = idx >> 2, c16 = idx & 3;
            const short8 v = *(const short8*)&srcs[tile][(size_t)row*Dc + k0 + c16*8];
            *(short8*)&lds[tile*5120 + row*40 + c16*8] = v;
        }
        __syncthreads();

        short8 fa0h[4], fa0l[4], fa1h[4], fa1l[4];
        #pragma unroll
        for (int i = 0; i < 4; ++i) {
            const int off = (wm*64 + i*16 + lrow)*40 + lg*8;
            fa0h[i] = *(const short8*)&lds[off];
            fa0l[i] = *(const short8*)&lds[5120  + off];
            fa1h[i] = *(const short8*)&lds[10240 + off];
            fa1l[i] = *(const short8*)&lds[15360 + off];
        }
        #pragma unroll
        for (int j = 0; j < 4; ++j) {
            const int ob = (wn*64 + j*16 + lrow)*40 + lg*8;
            const short8 fqh = *(const short8*)&lds[20480 + ob];
            const short8 fql = *(const short8*)&lds[25600 + ob];
            const short8 fkh = *(const short8*)&lds[30720 + ob];
            const short8 fkl = *(const short8*)&lds[35840 + ob];
            #pragma unroll
            for (int i = 0; i < 4; ++i) {
                accq[i][j] = __builtin_amdgcn_mfma_f32_16x16x32_bf16(fa0h[i], fqh, accq[i][j], 0, 0, 0);
                accq[i][j] = __builtin_amdgcn_mfma_f32_16x16x32_bf16(fa0h[i], fql, accq[i][j], 0, 0, 0);
                accq[i][j] = __builtin_amdgcn_mfma_f32_16x16x32_bf16(fa0l[i], fqh, accq[i][j], 0, 0, 0);
                acck[i][j] = __builtin_amdgcn_mfma_f32_16x16x32_bf16(fa1h[i], fkh, acck[i][j], 0, 0, 0);
                acck[i][j] = __builtin_amdgcn_mfma_f32_16x16x32_bf16(fa1h[i], fkl, acck[i][j], 0, 0, 0);
                acck[i][j] = __builtin_amdgcn_mfma_f32_16x16x32_bf16(fa1l[i], fkh, acck[i][j], 0, 0, 0);
            }
        }
        __syncthreads();
    }

    // ---- epilogue: per-row dot/qn/kn over this WG's 128 cols ----
    #pragma unroll
    for (int i = 0; i < 4; ++i) {
        #pragma unroll
        for (int reg = 0; reg < 4; ++reg) {
            float d = 0.f, qq = 0.f, kk = 0.f;
            #pragma unroll
            for (int j = 0; j < 4; ++j) {
                const float qv = accq[i][j][reg];
                const float kv = acck[i][j][reg];
                d  += qv * kv;
                qq += qv * qv;
                kk += kv * kv;
            }
            #pragma unroll
            for (int m = 1; m <= 8; m <<= 1) {
                d  += __shfl_xor(d,  m);
                qq += __shfl_xor(qq, m);
                kk += __shfl_xor(kk, m);
            }
            if ((lane & 15) == 0) {
                const int row = bm*128 + wm*64 + i*16 + ((lane >> 4) << 2) + reg;
                atomicAdd(&parts2[row],        d);
                atomicAdd(&parts2[1024 + row], qq);
                atomicAdd(&parts2[2048 + row], kk);
            }
        }
    }
}

__global__ __launch_bounds__(256)
void repair_fin_kernel(const float* __restrict__ parts2,
                       const int* __restrict__ flags,
                       float* __restrict__ cosv)
{
    const int fi = blockIdx.x*256 + threadIdx.x;
    const int count = min(flags[0], 1024);
    if (fi >= count) return;
    const float dot = parts2[fi];
    const float qn  = parts2[1024 + fi];
    const float kn  = parts2[2048 + fi];
    cosv[flags[1 + fi]] = dot / (fmaxf(sqrtf(qn), 1e-12f) * fmaxf(sqrtf(kn), 1e-12f));
}

// ---------------------------------------------------------------------------
// EMA scan — branchless; NSEG=128 (SEGLEN=32). (unchanged)
// ---------------------------------------------------------------------------
__device__ inline void build_seg_coefs(const float* __restrict__ cosv,
                                       int b, int l0,
                                       float* decA, float* wB)
{
    const int tid = threadIdx.x;
    if (tid < SEGLEN) {
        const int l = l0 + tid;
        float p;
        if (l == 0) {
            p = 1.f;
        } else {
            const float c = cosv[b*Lc + l - 1];
            p = fminf(fmaxf((1.f - c) * 0.5f, 0.f), 1.f);
        }
        const bool m = p > 0.5f;
        decA[tid] = m ? (1.f - p) : 1.f;
        wB[tid]   = m ? p : 0.f;
    }
    __syncthreads();
}

__global__ __launch_bounds__(256)
void seg_pass1_kernel(const float* __restrict__ X,
                      const float* __restrict__ cosv,
                      float* __restrict__ Aseg,
                      float* __restrict__ Bseg)
{
    __shared__ float decA[SEGLEN];
    __shared__ float wB[SEGLEN];
    const int tid = threadIdx.x;
    const int b = blockIdx.x >> 7;
    const int s = blockIdx.x & 127;
    const int l0 = s * SEGLEN;
    build_seg_coefs(cosv, b, l0, decA, wB);

    float4 st = make_float4(0.f, 0.f, 0.f, 0.f);
    float A = 1.f;
    const float* xb = X + (size_t)(b*Lc + l0)*Dc + tid*4;
    #pragma unroll 8
    for (int i = 0; i < SEGLEN; i++) {
        const float a = decA[i], w = wB[i];
        const float4 xv = *(const float4*)(xb + (size_t)i*Dc);
        st.x = a*st.x + w*xv.x;
        st.y = a*st.y + w*xv.y;
        st.z = a*st.z + w*xv.z;
        st.w = a*st.w + w*xv.w;
        A *= a;
    }
    *(float4*)&Bseg[(size_t)blockIdx.x*Dc + tid*4] = st;
    if (tid == 0) Aseg[blockIdx.x] = A;
}

__global__ __launch_bounds__(256)
void seg_combine_kernel(const float* __restrict__ Aseg,
                        const float* __restrict__ Bseg,
                        const float* __restrict__ init_state,
                        float* __restrict__ carry)
{
    const int tid = threadIdx.x;
    const int b  = blockIdx.x >> 2;
    const int d  = ((blockIdx.x & 3) << 8) + tid;
    float c = init_state[(size_t)b*Dc + d];
    for (int s = 0; s < NSEG; s++) {
        const size_t idx = (size_t)(b*NSEG + s);
        carry[idx*Dc + d] = c;
        c = Aseg[idx]*c + Bseg[idx*Dc + d];
    }
}

__global__ __launch_bounds__(256)
void seg_pass2_kernel(const float* __restrict__ X,
                      const float* __restrict__ RES,
                      const float* __restrict__ cosv,
                      const float* __restrict__ carry,
                      float* __restrict__ OUT)
{
    __shared__ float decA[SEGLEN];
    __shared__ float wB[SEGLEN];
    const int tid = threadIdx.x;
    const int b = blockIdx.x >> 7;
    const int s = blockIdx.x & 127;
    const int l0 = s * SEGLEN;
    build_seg_coefs(cosv, b, l0, decA, wB);

    float4 st = *(const float4*)&carry[(size_t)blockIdx.x*Dc + tid*4];
    const size_t base = (size_t)(b*Lc + l0)*Dc + tid*4;
    const float* xb = X   + base;
    const float* rb = RES + base;
    float*       ob = OUT + base;
    #pragma unroll 4
    for (int i = 0; i < SEGLEN; i++) {
        const float a = decA[i], w = wB[i];
        const float4 xv = *(const float4*)(xb + (size_t)i*Dc);
        const float4 rv = *(const float4*)(rb + (size_t)i*Dc);
        st.x = a*st.x + w*xv.x;
        st.y = a*st.y + w*xv.y;
        st.z = a*st.z + w*xv.z;
        st.w = a*st.w + w*xv.w;
        float4 ov;
        ov.x = rv.x + st.x;
        ov.y = rv.y + st.y;
        ov.z = rv.z + st.z;
        ov.w = rv.w + st.w;
        *(float4*)(ob + (size_t)i*Dc) = ov;
    }
}

// ---------------------------------------------------------------------------
extern "C" void kernel_launch(void* const* d_in, const int* in_sizes, int n_in,
                              void* d_out, int out_size, void* d_ws, size_t ws_size,
                              hipStream_t stream)
{
    const float* X    = (const float*)d_in[0];
    const float* RES  = (const float*)d_in[1];
    const float* QW   = (const float*)d_in[2];
    const float* KW   = (const float*)d_in[3];
    const float* INIT = (const float*)d_in[4];
    float* OUT = (float*)d_out;

    char* ws = (char*)d_ws;
    us*    Qh    = (us*)   (ws + OFF_QH);
    us*    Ql    = (us*)   (ws + OFF_QL);
    us*    Kh    = (us*)   (ws + OFF_KH);
    us*    Kl    = (us*)   (ws + OFF_KL);
    us*    Xbf   = (us*)   (ws + OFF_XBF);
    us*    GX0H  = (us*)   (ws + OFF_GX0H);
    us*    GX0L  = (us*)   (ws + OFF_GX0L);
    us*    GX1H  = (us*)   (ws + OFF_GX1H);
    us*    GX1L  = (us*)   (ws + OFF_GX1L);
    float* parts2= (float*)(ws + OFF_P2);
    float* parts = (float*)(ws + OFF_PARTS);
    int*   flags = (int*)  (ws + OFF_FLAGS);
    float* cosv  = (float*)(ws + OFF_COSV);
    float* Aseg  = (float*)(ws + OFF_ASEG);
    float* Bseg  = (float*)(ws + OFF_BSEG);
    float* carry = (float*)(ws + OFF_CARRY);

    prep_kernel      <<<2752, 256, 0, stream>>>(QW, KW, X, Qh, Ql, Kh, Kl, Xbf, parts, flags);
    gemm_cos_kernel  <<<1024, 256, 0, stream>>>(Xbf, Qh, Kh, parts);
    cos_fin_kernel   <<<64,   256, 0, stream>>>(parts, cosv, flags, parts2);
    gather_kernel    <<<1024, 256, 0, stream>>>(X, flags, GX0H, GX0L, GX1H, GX1L);
    repair_gemm_kernel<<<64,  256, 0, stream>>>(GX0H, GX0L, GX1H, GX1L, Qh, Ql, Kh, Kl, flags, parts2);
    repair_fin_kernel<<<4,    256, 0, stream>>>(parts2, flags, cosv);
    seg_pass1_kernel  <<<Bc*NSEG, 256, 0, stream>>>(X, cosv, Aseg, Bseg);
    seg_combine_kernel<<<Bc*4,    256, 0, stream>>>(Aseg, Bseg, INIT, carry);
    seg_pass2_kernel  <<<Bc*NSEG, 256, 0, stream>>>(X, RES, cosv, carry, OUT);
}